// Round 1
// baseline (1568.370 us; speedup 1.0000x reference)
//
#include <hip/hip_runtime.h>
#include <math.h>

#define BB 8
#define LL 1024
#define EE 512
#define HH 8
#define HD 64
#define PP 2047

static constexpr float SCALE = 0.04419417382415922f; // 1/sqrt(512)

// ---------------------------------------------------------------------------
// Generic 64x64-tile fp32 GEMM pieces: C[m,n] = sum_k A[m,k]*W[n,k]
// A: (M,512) row-major, W: (N,512) row-major. Block 256 thr, thread 4x4.
// LDS tiles stored K-major (transposed) so compute reads are float4.
// ---------------------------------------------------------------------------

__global__ __launch_bounds__(256) void qkv_kernel(
    const float* __restrict__ x,      // (B*L, E)
    const float* __restrict__ w,      // (3E, E)
    const float* __restrict__ ubias,  // flat 512 (reshape(H,HD): [h*64+d])
    const float* __restrict__ vbias,  // flat 512
    float* __restrict__ Qu, float* __restrict__ Qv,
    float* __restrict__ Kw, float* __restrict__ Vw)
{
    const int m0 = blockIdx.y * 64;
    const int n0 = blockIdx.x * 64;
    const int tid = threadIdx.x;
    const int tx = tid & 15, ty = tid >> 4;

    __shared__ float At[16][68];
    __shared__ float Bt[16][68];

    float acc[4][4];
#pragma unroll
    for (int i = 0; i < 4; i++)
#pragma unroll
        for (int j = 0; j < 4; j++) acc[i][j] = 0.f;

    const int lrow = tid >> 2;       // 0..63
    const int lk4  = (tid & 3) * 4;  // 0,4,8,12

    for (int kt = 0; kt < EE; kt += 16) {
        float4 av = *(const float4*)&x[(size_t)(m0 + lrow) * EE + kt + lk4];
        float4 bv = *(const float4*)&w[(size_t)(n0 + lrow) * EE + kt + lk4];
        __syncthreads();
        At[lk4 + 0][lrow] = av.x; At[lk4 + 1][lrow] = av.y;
        At[lk4 + 2][lrow] = av.z; At[lk4 + 3][lrow] = av.w;
        Bt[lk4 + 0][lrow] = bv.x; Bt[lk4 + 1][lrow] = bv.y;
        Bt[lk4 + 2][lrow] = bv.z; Bt[lk4 + 3][lrow] = bv.w;
        __syncthreads();
#pragma unroll
        for (int kk = 0; kk < 16; kk++) {
            float4 a = *(const float4*)&At[kk][ty * 4];
            float4 b = *(const float4*)&Bt[kk][tx * 4];
            float aa[4] = {a.x, a.y, a.z, a.w};
            float bb[4] = {b.x, b.y, b.z, b.w};
#pragma unroll
            for (int i = 0; i < 4; i++)
#pragma unroll
                for (int j = 0; j < 4; j++) acc[i][j] += aa[i] * bb[j];
        }
    }

#pragma unroll
    for (int i = 0; i < 4; i++) {
        int m = m0 + ty * 4 + i;
        int b = m >> 10, l = m & 1023;
#pragma unroll
        for (int j = 0; j < 4; j++) {
            int n = n0 + tx * 4 + j;
            int h = n / 192;
            int r = n - h * 192;
            int cls = r >> 6;
            int d = r & 63;
            size_t idx = ((size_t)(b * HH + h) * LL + l) * HD + d;
            float v = acc[i][j];
            if (cls == 0) {
                Qu[idx] = (v + ubias[h * 64 + d]) * SCALE;
                Qv[idx] = (v + vbias[h * 64 + d]) * SCALE;
            } else if (cls == 1) {
                Kw[idx] = v;
            } else {
                Vw[idx] = v;
            }
        }
    }
}

__global__ __launch_bounds__(256) void posk_kernel(
    const float* __restrict__ pe,  // (P, E)
    const float* __restrict__ w,   // (E, E)
    float* __restrict__ pko)       // (H, P, HD)
{
    const int m0 = blockIdx.y * 64;
    const int n0 = blockIdx.x * 64;
    const int tid = threadIdx.x;
    const int tx = tid & 15, ty = tid >> 4;

    __shared__ float At[16][68];
    __shared__ float Bt[16][68];

    float acc[4][4];
#pragma unroll
    for (int i = 0; i < 4; i++)
#pragma unroll
        for (int j = 0; j < 4; j++) acc[i][j] = 0.f;

    const int lrow = tid >> 2;
    const int lk4  = (tid & 3) * 4;
    const int grow = m0 + lrow;

    for (int kt = 0; kt < EE; kt += 16) {
        float4 av = make_float4(0.f, 0.f, 0.f, 0.f);
        if (grow < PP) av = *(const float4*)&pe[(size_t)grow * EE + kt + lk4];
        float4 bv = *(const float4*)&w[(size_t)(n0 + lrow) * EE + kt + lk4];
        __syncthreads();
        At[lk4 + 0][lrow] = av.x; At[lk4 + 1][lrow] = av.y;
        At[lk4 + 2][lrow] = av.z; At[lk4 + 3][lrow] = av.w;
        Bt[lk4 + 0][lrow] = bv.x; Bt[lk4 + 1][lrow] = bv.y;
        Bt[lk4 + 2][lrow] = bv.z; Bt[lk4 + 3][lrow] = bv.w;
        __syncthreads();
#pragma unroll
        for (int kk = 0; kk < 16; kk++) {
            float4 a = *(const float4*)&At[kk][ty * 4];
            float4 b = *(const float4*)&Bt[kk][tx * 4];
            float aa[4] = {a.x, a.y, a.z, a.w};
            float bb[4] = {b.x, b.y, b.z, b.w};
#pragma unroll
            for (int i = 0; i < 4; i++)
#pragma unroll
                for (int j = 0; j < 4; j++) acc[i][j] += aa[i] * bb[j];
        }
    }

#pragma unroll
    for (int i = 0; i < 4; i++) {
        int p = m0 + ty * 4 + i;
        if (p >= PP) continue;
#pragma unroll
        for (int j = 0; j < 4; j++) {
            int n = n0 + tx * 4 + j;
            int h = n >> 6, d = n & 63;
            pko[((size_t)h * PP + p) * HD + d] = acc[i][j];
        }
    }
}

__global__ __launch_bounds__(256) void outproj_kernel(
    const float* __restrict__ ctx,  // (B*L, E)
    const float* __restrict__ w,    // (E, E)
    const float* __restrict__ bias, // (E,)
    float* __restrict__ out)        // (B*L, E)
{
    const int m0 = blockIdx.y * 64;
    const int n0 = blockIdx.x * 64;
    const int tid = threadIdx.x;
    const int tx = tid & 15, ty = tid >> 4;

    __shared__ float At[16][68];
    __shared__ float Bt[16][68];

    float acc[4][4];
#pragma unroll
    for (int i = 0; i < 4; i++)
#pragma unroll
        for (int j = 0; j < 4; j++) acc[i][j] = 0.f;

    const int lrow = tid >> 2;
    const int lk4  = (tid & 3) * 4;

    for (int kt = 0; kt < EE; kt += 16) {
        float4 av = *(const float4*)&ctx[(size_t)(m0 + lrow) * EE + kt + lk4];
        float4 bv = *(const float4*)&w[(size_t)(n0 + lrow) * EE + kt + lk4];
        __syncthreads();
        At[lk4 + 0][lrow] = av.x; At[lk4 + 1][lrow] = av.y;
        At[lk4 + 2][lrow] = av.z; At[lk4 + 3][lrow] = av.w;
        Bt[lk4 + 0][lrow] = bv.x; Bt[lk4 + 1][lrow] = bv.y;
        Bt[lk4 + 2][lrow] = bv.z; Bt[lk4 + 3][lrow] = bv.w;
        __syncthreads();
#pragma unroll
        for (int kk = 0; kk < 16; kk++) {
            float4 a = *(const float4*)&At[kk][ty * 4];
            float4 b = *(const float4*)&Bt[kk][tx * 4];
            float aa[4] = {a.x, a.y, a.z, a.w};
            float bb[4] = {b.x, b.y, b.z, b.w};
#pragma unroll
            for (int i = 0; i < 4; i++)
#pragma unroll
                for (int j = 0; j < 4; j++) acc[i][j] += aa[i] * bb[j];
        }
    }

#pragma unroll
    for (int i = 0; i < 4; i++) {
        int m = m0 + ty * 4 + i;
#pragma unroll
        for (int j = 0; j < 4; j++) {
            int n = n0 + tx * 4 + j;
            out[(size_t)m * EE + n] = acc[i][j] + bias[n];
        }
    }
}

// ---------------------------------------------------------------------------
// Fused attention: per block = (b, h, 16 q-rows). Computes
// logit[q,k] = Qu_row . K_k  +  Qv_row . pk[k-q+1023]   (scale prebaked)
// then softmax (writes attn) then PV (writes ctx).
// ---------------------------------------------------------------------------
__global__ __launch_bounds__(256) void attn_kernel(
    const float* __restrict__ Qu, const float* __restrict__ Qv,
    const float* __restrict__ Kw, const float* __restrict__ Vw,
    const float* __restrict__ pk,   // (H, P, HD)
    float* __restrict__ attn,       // (B, H, L, L)
    float* __restrict__ ctx)        // (B, L, E)
{
    const int b = blockIdx.z, h = blockIdx.y, q0 = blockIdx.x * 16;
    const int tid = threadIdx.x;
    const int q = tid >> 4;    // 0..15 local q row
    const int kq = tid & 15;   // 0..15: covers k = kq*4..kq*4+3 per tile

    __shared__ float QU[16][65];
    __shared__ float QV[16][65];
    __shared__ float TILE[64][68];   // phase1: K^T (d-major). phase2: V (k-major)
    __shared__ float PKs[79][65];    // pos-key window, p-major
    __shared__ float PT[16][68];     // probs staging for PV

    const float* qu_base = Qu + ((size_t)(b * HH + h) * LL + q0) * HD;
    const float* qv_base = Qv + ((size_t)(b * HH + h) * LL + q0) * HD;
    const float* k_base  = Kw + (size_t)(b * HH + h) * LL * HD;
    const float* v_base  = Vw + (size_t)(b * HH + h) * LL * HD;
    const float* pk_base = pk + (size_t)h * PP * HD;

    // load QU/QV tiles: 16 rows x 64 -> one float4 per thread
    {
        int row = tid >> 4, c4 = (tid & 15) * 4;
        float4 a  = *(const float4*)&qu_base[row * HD + c4];
        float4 bv = *(const float4*)&qv_base[row * HD + c4];
        QU[row][c4 + 0] = a.x;  QU[row][c4 + 1] = a.y;
        QU[row][c4 + 2] = a.z;  QU[row][c4 + 3] = a.w;
        QV[row][c4 + 0] = bv.x; QV[row][c4 + 1] = bv.y;
        QV[row][c4 + 2] = bv.z; QV[row][c4 + 3] = bv.w;
    }

    float lg[64];
#pragma unroll
    for (int i = 0; i < 64; i++) lg[i] = 0.f;

#pragma unroll
    for (int kt = 0; kt < 16; kt++) {
        const int k0 = kt * 64;
        const int p_base = k0 - q0 + 1008;  // always in [0, 1968]
        __syncthreads();
        // stage K tile transposed: TILE[d][k]
#pragma unroll
        for (int i = 0; i < 4; i++) {
            int idx = tid + 256 * i;            // 0..1023
            int krow = idx >> 4, d4 = (idx & 15) * 4;
            float4 v = *(const float4*)&k_base[(size_t)(k0 + krow) * HD + d4];
            TILE[d4 + 0][krow] = v.x; TILE[d4 + 1][krow] = v.y;
            TILE[d4 + 2][krow] = v.z; TILE[d4 + 3][krow] = v.w;
        }
        // stage pos-key window: PKs[p][d], 79 rows
#pragma unroll
        for (int i = 0; i < 5; i++) {
            int idx = tid + 256 * i;
            if (idx < 79 * 16) {
                int prow = idx >> 4, d4 = (idx & 15) * 4;
                float4 v = *(const float4*)&pk_base[(size_t)(p_base + prow) * HD + d4];
                PKs[prow][d4 + 0] = v.x; PKs[prow][d4 + 1] = v.y;
                PKs[prow][d4 + 2] = v.z; PKs[prow][d4 + 3] = v.w;
            }
        }
        __syncthreads();
#pragma unroll 4
        for (int d = 0; d < 64; d++) {
            float au = QU[q][d];
            float av = QV[q][d];
            float4 kv = *(const float4*)&TILE[d][kq * 4];
            float kk4[4] = {kv.x, kv.y, kv.z, kv.w};
#pragma unroll
            for (int i = 0; i < 4; i++) {
                int r = kq * 4 + i - q + 15;   // in [0,78]
                lg[kt * 4 + i] += au * kk4[i] + av * PKs[r][d];
            }
        }
    }

    // ---- softmax over the q-row (16 threads per row, 64 logits each) ----
    float mx = -1e30f;
#pragma unroll
    for (int i = 0; i < 64; i++) mx = fmaxf(mx, lg[i]);
#pragma unroll
    for (int off = 8; off >= 1; off >>= 1) mx = fmaxf(mx, __shfl_xor(mx, off, 16));
    float s = 0.f;
#pragma unroll
    for (int i = 0; i < 64; i++) { lg[i] = __expf(lg[i] - mx); s += lg[i]; }
#pragma unroll
    for (int off = 8; off >= 1; off >>= 1) s += __shfl_xor(s, off, 16);
    const float inv = 1.0f / s;

    float* attn_row = attn + (((size_t)(b * HH + h) * LL) + q0 + q) * LL;
#pragma unroll
    for (int kt = 0; kt < 16; kt++) {
        float4 pv;
        pv.x = lg[kt * 4 + 0] * inv;
        pv.y = lg[kt * 4 + 1] * inv;
        pv.z = lg[kt * 4 + 2] * inv;
        pv.w = lg[kt * 4 + 3] * inv;
        lg[kt * 4 + 0] = pv.x; lg[kt * 4 + 1] = pv.y;
        lg[kt * 4 + 2] = pv.z; lg[kt * 4 + 3] = pv.w;
        *(float4*)&attn_row[kt * 64 + kq * 4] = pv;
    }

    // ---- PV: ctx[q][d] = sum_k p[q,k] * V[k,d] ----
    float acc2[4] = {0.f, 0.f, 0.f, 0.f};
    const int d4 = kq * 4;
#pragma unroll
    for (int kt = 0; kt < 16; kt++) {
        __syncthreads();
#pragma unroll
        for (int i = 0; i < 4; i++) {
            int idx = tid + 256 * i;
            int krow = idx >> 4, dd4 = (idx & 15) * 4;
            float4 v = *(const float4*)&v_base[(size_t)(kt * 64 + krow) * HD + dd4];
            *(float4*)&TILE[krow][dd4] = v;
        }
        *(float4*)&PT[q][kq * 4] =
            make_float4(lg[kt * 4 + 0], lg[kt * 4 + 1], lg[kt * 4 + 2], lg[kt * 4 + 3]);
        __syncthreads();
#pragma unroll 8
        for (int kk = 0; kk < 64; kk++) {
            float sp = PT[q][kk];
            float4 vv = *(const float4*)&TILE[kk][d4];
            acc2[0] += sp * vv.x; acc2[1] += sp * vv.y;
            acc2[2] += sp * vv.z; acc2[3] += sp * vv.w;
        }
    }
    *(float4*)&ctx[((size_t)b * LL + q0 + q) * EE + h * HD + d4] =
        make_float4(acc2[0], acc2[1], acc2[2], acc2[3]);
}

// ---------------------------------------------------------------------------
extern "C" void kernel_launch(void* const* d_in, const int* in_sizes, int n_in,
                              void* d_out, int out_size, void* d_ws, size_t ws_size,
                              hipStream_t stream)
{
    const float* x   = (const float*)d_in[0];
    const float* pe  = (const float*)d_in[1];
    const float* ipw = (const float*)d_in[2];
    const float* lpw = (const float*)d_in[3];
    const float* opw = (const float*)d_in[4];
    const float* opb = (const float*)d_in[5];
    const float* pbu = (const float*)d_in[6];
    const float* pbv = (const float*)d_in[7];

    float* out  = (float*)d_out;                          // (B,L,E)
    float* attn = (float*)d_out + (size_t)BB * LL * EE;   // (B,H,L,L)

    float* ws = (float*)d_ws;
    float* Qu  = ws; ws += (size_t)BB * HH * LL * HD;
    float* Qv  = ws; ws += (size_t)BB * HH * LL * HD;
    float* Kw  = ws; ws += (size_t)BB * HH * LL * HD;
    float* Vw  = ws; ws += (size_t)BB * HH * LL * HD;
    float* pk  = ws; ws += (size_t)HH * PP * HD;
    float* ctx = ws; ws += (size_t)BB * LL * EE;

    qkv_kernel<<<dim3(24, 128), 256, 0, stream>>>(x, ipw, pbu, pbv, Qu, Qv, Kw, Vw);
    posk_kernel<<<dim3(8, 32), 256, 0, stream>>>(pe, lpw, pk);
    attn_kernel<<<dim3(64, 8, 8), 256, 0, stream>>>(Qu, Qv, Kw, Vw, pk, attn, ctx);
    outproj_kernel<<<dim3(8, 128), 256, 0, stream>>>(ctx, opw, opb, out);
}

// Round 2
// 735.310 us; speedup vs baseline: 2.1329x; 2.1329x over previous
//
#include <hip/hip_runtime.h>
#include <math.h>

#define BB 8
#define LL 1024
#define EE 512
#define HH 8
#define HD 64
#define PP 2047

static constexpr float SCALE = 0.04419417382415922f; // 1/sqrt(512)

typedef __bf16 bf16x8 __attribute__((ext_vector_type(8)));
typedef float f32x4 __attribute__((ext_vector_type(4)));

#define MFMA16(a, b, c) __builtin_amdgcn_mfma_f32_16x16x32_bf16(a, b, c, 0, 0, 0)

static __device__ __forceinline__ unsigned short f2bfbits(float f) {
    union { float f; unsigned u; } v; v.f = f;
    unsigned r = v.u + 0x7fffu + ((v.u >> 16) & 1u);
    return (unsigned short)(r >> 16);
}
static __device__ __forceinline__ float bfbits2f(unsigned short b) {
    union { unsigned u; float f; } v; v.u = ((unsigned)b) << 16;
    return v.f;
}

// ---------------------------------------------------------------------------
// fp32 vector GEMMs for the projections (bf16 outputs where attn consumes them)
// ---------------------------------------------------------------------------

__global__ __launch_bounds__(256) void qkv_kernel(
    const float* __restrict__ x,      // (B*L, E)
    const float* __restrict__ w,      // (3E, E)
    const float* __restrict__ ubias,  // flat 512
    const float* __restrict__ vbias,  // flat 512
    unsigned short* __restrict__ Qu,  // (B,H,L,HD) bf16, (q+u)*scale
    unsigned short* __restrict__ Qv,  // (B,H,L,HD) bf16, (q+v)*scale
    unsigned short* __restrict__ Kw,  // (B,H,L,HD) bf16
    unsigned short* __restrict__ Vt)  // (B,H,HD,L) bf16 (transposed!)
{
    const int m0 = blockIdx.y * 64;
    const int n0 = blockIdx.x * 64;
    const int tid = threadIdx.x;
    const int tx = tid & 15, ty = tid >> 4;

    __shared__ float At[16][68];
    __shared__ float Bt[16][68];

    float acc[4][4];
#pragma unroll
    for (int i = 0; i < 4; i++)
#pragma unroll
        for (int j = 0; j < 4; j++) acc[i][j] = 0.f;

    const int lrow = tid >> 2;
    const int lk4  = (tid & 3) * 4;

    for (int kt = 0; kt < EE; kt += 16) {
        float4 av = *(const float4*)&x[(size_t)(m0 + lrow) * EE + kt + lk4];
        float4 bv = *(const float4*)&w[(size_t)(n0 + lrow) * EE + kt + lk4];
        __syncthreads();
        At[lk4 + 0][lrow] = av.x; At[lk4 + 1][lrow] = av.y;
        At[lk4 + 2][lrow] = av.z; At[lk4 + 3][lrow] = av.w;
        Bt[lk4 + 0][lrow] = bv.x; Bt[lk4 + 1][lrow] = bv.y;
        Bt[lk4 + 2][lrow] = bv.z; Bt[lk4 + 3][lrow] = bv.w;
        __syncthreads();
#pragma unroll
        for (int kk = 0; kk < 16; kk++) {
            float4 a = *(const float4*)&At[kk][ty * 4];
            float4 b = *(const float4*)&Bt[kk][tx * 4];
            float aa[4] = {a.x, a.y, a.z, a.w};
            float bb[4] = {b.x, b.y, b.z, b.w};
#pragma unroll
            for (int i = 0; i < 4; i++)
#pragma unroll
                for (int j = 0; j < 4; j++) acc[i][j] += aa[i] * bb[j];
        }
    }

#pragma unroll
    for (int i = 0; i < 4; i++) {
        int m = m0 + ty * 4 + i;
        int b = m >> 10, l = m & 1023;
#pragma unroll
        for (int j = 0; j < 4; j++) {
            int n = n0 + tx * 4 + j;
            int h = n / 192;
            int r = n - h * 192;
            int cls = r >> 6;
            int d = r & 63;
            float v = acc[i][j];
            if (cls == 0) {
                size_t idx = ((size_t)(b * HH + h) * LL + l) * HD + d;
                Qu[idx] = f2bfbits((v + ubias[h * 64 + d]) * SCALE);
                Qv[idx] = f2bfbits((v + vbias[h * 64 + d]) * SCALE);
            } else if (cls == 1) {
                Kw[((size_t)(b * HH + h) * LL + l) * HD + d] = f2bfbits(v);
            } else {
                Vt[((size_t)(b * HH + h) * HD + d) * LL + l] = f2bfbits(v);
            }
        }
    }
}

__global__ __launch_bounds__(256) void posk_kernel(
    const float* __restrict__ pe,  // (P, E)
    const float* __restrict__ w,   // (E, E)
    unsigned short* __restrict__ pko)  // (H, P, HD) bf16
{
    const int m0 = blockIdx.y * 64;
    const int n0 = blockIdx.x * 64;
    const int tid = threadIdx.x;
    const int tx = tid & 15, ty = tid >> 4;

    __shared__ float At[16][68];
    __shared__ float Bt[16][68];

    float acc[4][4];
#pragma unroll
    for (int i = 0; i < 4; i++)
#pragma unroll
        for (int j = 0; j < 4; j++) acc[i][j] = 0.f;

    const int lrow = tid >> 2;
    const int lk4  = (tid & 3) * 4;
    const int grow = m0 + lrow;

    for (int kt = 0; kt < EE; kt += 16) {
        float4 av = make_float4(0.f, 0.f, 0.f, 0.f);
        if (grow < PP) av = *(const float4*)&pe[(size_t)grow * EE + kt + lk4];
        float4 bv = *(const float4*)&w[(size_t)(n0 + lrow) * EE + kt + lk4];
        __syncthreads();
        At[lk4 + 0][lrow] = av.x; At[lk4 + 1][lrow] = av.y;
        At[lk4 + 2][lrow] = av.z; At[lk4 + 3][lrow] = av.w;
        Bt[lk4 + 0][lrow] = bv.x; Bt[lk4 + 1][lrow] = bv.y;
        Bt[lk4 + 2][lrow] = bv.z; Bt[lk4 + 3][lrow] = bv.w;
        __syncthreads();
#pragma unroll
        for (int kk = 0; kk < 16; kk++) {
            float4 a = *(const float4*)&At[kk][ty * 4];
            float4 b = *(const float4*)&Bt[kk][tx * 4];
            float aa[4] = {a.x, a.y, a.z, a.w};
            float bb[4] = {b.x, b.y, b.z, b.w};
#pragma unroll
            for (int i = 0; i < 4; i++)
#pragma unroll
                for (int j = 0; j < 4; j++) acc[i][j] += aa[i] * bb[j];
        }
    }

#pragma unroll
    for (int i = 0; i < 4; i++) {
        int p = m0 + ty * 4 + i;
        if (p >= PP) continue;
#pragma unroll
        for (int j = 0; j < 4; j++) {
            int n = n0 + tx * 4 + j;
            int h = n >> 6, d = n & 63;
            pko[((size_t)h * PP + p) * HD + d] = f2bfbits(acc[i][j]);
        }
    }
}

__global__ __launch_bounds__(256) void outproj_kernel(
    const float* __restrict__ ctx,  // (B*L, E)
    const float* __restrict__ w,    // (E, E)
    const float* __restrict__ bias, // (E,)
    float* __restrict__ out)        // (B*L, E)
{
    const int m0 = blockIdx.y * 64;
    const int n0 = blockIdx.x * 64;
    const int tid = threadIdx.x;
    const int tx = tid & 15, ty = tid >> 4;

    __shared__ float At[16][68];
    __shared__ float Bt[16][68];

    float acc[4][4];
#pragma unroll
    for (int i = 0; i < 4; i++)
#pragma unroll
        for (int j = 0; j < 4; j++) acc[i][j] = 0.f;

    const int lrow = tid >> 2;
    const int lk4  = (tid & 3) * 4;

    for (int kt = 0; kt < EE; kt += 16) {
        float4 av = *(const float4*)&ctx[(size_t)(m0 + lrow) * EE + kt + lk4];
        float4 bv = *(const float4*)&w[(size_t)(n0 + lrow) * EE + kt + lk4];
        __syncthreads();
        At[lk4 + 0][lrow] = av.x; At[lk4 + 1][lrow] = av.y;
        At[lk4 + 2][lrow] = av.z; At[lk4 + 3][lrow] = av.w;
        Bt[lk4 + 0][lrow] = bv.x; Bt[lk4 + 1][lrow] = bv.y;
        Bt[lk4 + 2][lrow] = bv.z; Bt[lk4 + 3][lrow] = bv.w;
        __syncthreads();
#pragma unroll
        for (int kk = 0; kk < 16; kk++) {
            float4 a = *(const float4*)&At[kk][ty * 4];
            float4 b = *(const float4*)&Bt[kk][tx * 4];
            float aa[4] = {a.x, a.y, a.z, a.w};
            float bb[4] = {b.x, b.y, b.z, b.w};
#pragma unroll
            for (int i = 0; i < 4; i++)
#pragma unroll
                for (int j = 0; j < 4; j++) acc[i][j] += aa[i] * bb[j];
        }
    }

#pragma unroll
    for (int i = 0; i < 4; i++) {
        int m = m0 + ty * 4 + i;
#pragma unroll
        for (int j = 0; j < 4; j++) {
            int n = n0 + tx * 4 + j;
            out[(size_t)m * EE + n] = acc[i][j] + bias[n];
        }
    }
}

// ---------------------------------------------------------------------------
// MFMA fused attention. Block = (b, h, 16 q-rows); 4 waves split k (256 each).
// logit[q,k] = Qu[q].K[k] + Qv[q].pk[k-q+1023]; softmax; attn write; PV.
// ---------------------------------------------------------------------------
__global__ __launch_bounds__(256, 3) void attn_kernel(
    const unsigned short* __restrict__ Qu, const unsigned short* __restrict__ Qv,
    const unsigned short* __restrict__ Kw, const unsigned short* __restrict__ Vt,
    const unsigned short* __restrict__ pk,  // (H,P,HD) bf16
    float* __restrict__ attn,               // (B,H,L,L)
    float* __restrict__ ctx)                // (B,L,E)
{
    const int b = blockIdx.z, h = blockIdx.y, q0 = blockIdx.x * 16;
    const int tid = threadIdx.x;
    const int w = tid >> 6, lane = tid & 63;
    const int g = lane >> 4, c16 = lane & 15;
    const int bh = b * HH + h;

    __shared__ unsigned short BDG[4][16 * 152];  // per-wave: BD window gemm / P staging
    __shared__ float SMmax[4][16];
    __shared__ float SMsum[4][16];
    __shared__ float CTX[4][16 * 68];

    // resident A-fragments (A[m=lane&15][k=g*8+j]): direct 16B global loads
    const unsigned short* qub = Qu + ((size_t)bh * LL + q0 + c16) * HD + g * 8;
    const unsigned short* qvb = Qv + ((size_t)bh * LL + q0 + c16) * HD + g * 8;
    bf16x8 au0 = *(const bf16x8*)qub;
    bf16x8 au1 = *(const bf16x8*)(qub + 32);
    bf16x8 av0 = *(const bf16x8*)qvb;
    bf16x8 av1 = *(const bf16x8*)(qvb + 32);

    f32x4 lg[16];
#pragma unroll
    for (int t = 0; t < 16; t++) lg[t] = (f32x4){0.f, 0.f, 0.f, 0.f};

    const unsigned short* kbase  = Kw + (size_t)bh * LL * HD;
    const unsigned short* pkbase = pk + (size_t)h * PP * HD;

#pragma unroll
    for (int p = 0; p < 2; p++) {
        const int kp = w * 256 + p * 128;
        const int pstart = kp - q0 + 1008;  // window col 0 -> p index
        // BD window gemm: 16 q x 144 cols, staged bf16 in LDS
#pragma unroll
        for (int ct = 0; ct < 9; ct++) {
            int prow = pstart + ct * 16 + c16;
            prow = prow > (PP - 1) ? (PP - 1) : prow;  // col 143 pad, never gathered
            const unsigned short* pb = pkbase + (size_t)prow * HD + g * 8;
            f32x4 acc = (f32x4){0.f, 0.f, 0.f, 0.f};
            acc = MFMA16(av0, *(const bf16x8*)pb, acc);
            acc = MFMA16(av1, *(const bf16x8*)(pb + 32), acc);
#pragma unroll
            for (int r = 0; r < 4; r++)
                BDG[w][(g * 4 + r) * 152 + ct * 16 + c16] = f2bfbits(acc[r]);
        }
        // AC: B-frag = K rows, direct global 16B loads
#pragma unroll
        for (int jt = 0; jt < 8; jt++) {
            const unsigned short* kb = kbase + (size_t)(kp + jt * 16 + c16) * HD + g * 8;
            int t = p * 8 + jt;
            lg[t] = MFMA16(au0, *(const bf16x8*)kb, lg[t]);
            lg[t] = MFMA16(au1, *(const bf16x8*)(kb + 32), lg[t]);
        }
        __syncthreads();
        // diagonal gather: BD[i][j] = BDG[i][j - i + 15]
#pragma unroll
        for (int jt = 0; jt < 8; jt++) {
            int t = p * 8 + jt;
#pragma unroll
            for (int r = 0; r < 4; r++) {
                int i = g * 4 + r;
                int c = jt * 16 + c16 - i + 15;
                lg[t][r] += bfbits2f(BDG[w][i * 152 + c]);
            }
        }
        __syncthreads();
    }

    // ---- softmax over full 1024 keys ----
    float M[4], Sv[4], inv[4];
#pragma unroll
    for (int r = 0; r < 4; r++) {
        float m = lg[0][r];
#pragma unroll
        for (int t = 1; t < 16; t++) m = fmaxf(m, lg[t][r]);
        M[r] = m;
    }
#pragma unroll
    for (int off = 8; off >= 1; off >>= 1)
#pragma unroll
        for (int r = 0; r < 4; r++) M[r] = fmaxf(M[r], __shfl_xor(M[r], off, 16));
    if (c16 == 0) {
#pragma unroll
        for (int r = 0; r < 4; r++) SMmax[w][g * 4 + r] = M[r];
    }
    __syncthreads();
#pragma unroll
    for (int r = 0; r < 4; r++) {
        int row = g * 4 + r;
        M[r] = fmaxf(fmaxf(SMmax[0][row], SMmax[1][row]),
                     fmaxf(SMmax[2][row], SMmax[3][row]));
        Sv[r] = 0.f;
    }
#pragma unroll
    for (int t = 0; t < 16; t++)
#pragma unroll
        for (int r = 0; r < 4; r++) {
            float e = __expf(lg[t][r] - M[r]);
            lg[t][r] = e;
            Sv[r] += e;
        }
#pragma unroll
    for (int off = 8; off >= 1; off >>= 1)
#pragma unroll
        for (int r = 0; r < 4; r++) Sv[r] += __shfl_xor(Sv[r], off, 16);
    if (c16 == 0) {
#pragma unroll
        for (int r = 0; r < 4; r++) SMsum[w][g * 4 + r] = Sv[r];
    }
    __syncthreads();
#pragma unroll
    for (int r = 0; r < 4; r++) {
        int row = g * 4 + r;
        inv[r] = 1.0f / (SMsum[0][row] + SMsum[1][row] + SMsum[2][row] + SMsum[3][row]);
    }

    // ---- normalize + write attn ----
    float* arow = attn + (size_t)bh * LL * LL;
#pragma unroll
    for (int t = 0; t < 16; t++)
#pragma unroll
        for (int r = 0; r < 4; r++) {
            float pr = lg[t][r] * inv[r];
            lg[t][r] = pr;
            arow[(size_t)(q0 + g * 4 + r) * LL + w * 256 + t * 16 + c16] = pr;
        }

    // ---- PV: ctx[q][d] = sum_k P[q,k] V[k,d], B from transposed V ----
    f32x4 cacc[4];
#pragma unroll
    for (int nt = 0; nt < 4; nt++) cacc[nt] = (f32x4){0.f, 0.f, 0.f, 0.f};

#pragma unroll
    for (int p = 0; p < 2; p++) {
        const int kp = w * 256 + p * 128;
        __syncthreads();
        // stage P (C-layout -> A-layout via LDS), bf16
#pragma unroll
        for (int jt = 0; jt < 8; jt++) {
            int t = p * 8 + jt;
#pragma unroll
            for (int r = 0; r < 4; r++)
                BDG[w][(g * 4 + r) * 152 + jt * 16 + c16] = f2bfbits(lg[t][r]);
        }
        __syncthreads();
        bf16x8 pa[4];
#pragma unroll
        for (int kk = 0; kk < 4; kk++)
            pa[kk] = *(const bf16x8*)&BDG[w][c16 * 152 + kk * 32 + g * 8];
#pragma unroll
        for (int kk = 0; kk < 4; kk++) {
#pragma unroll
            for (int nt = 0; nt < 4; nt++) {
                const unsigned short* vb =
                    Vt + ((size_t)bh * HD + nt * 16 + c16) * LL + kp + kk * 32 + g * 8;
                cacc[nt] = MFMA16(pa[kk], *(const bf16x8*)vb, cacc[nt]);
            }
        }
    }

    // ---- cross-wave ctx reduction ----
    __syncthreads();
#pragma unroll
    for (int nt = 0; nt < 4; nt++)
#pragma unroll
        for (int r = 0; r < 4; r++)
            CTX[w][(g * 4 + r) * 68 + nt * 16 + c16] = cacc[nt][r];
    __syncthreads();
    {
        int row = tid >> 4, d4 = (tid & 15) * 4;
        f32x4 s = *(const f32x4*)&CTX[0][row * 68 + d4];
        s += *(const f32x4*)&CTX[1][row * 68 + d4];
        s += *(const f32x4*)&CTX[2][row * 68 + d4];
        s += *(const f32x4*)&CTX[3][row * 68 + d4];
        *(f32x4*)&ctx[((size_t)b * LL + q0 + row) * EE + h * HD + d4] = s;
    }
}

// ---------------------------------------------------------------------------
extern "C" void kernel_launch(void* const* d_in, const int* in_sizes, int n_in,
                              void* d_out, int out_size, void* d_ws, size_t ws_size,
                              hipStream_t stream)
{
    const float* x   = (const float*)d_in[0];
    const float* pe  = (const float*)d_in[1];
    const float* ipw = (const float*)d_in[2];
    const float* lpw = (const float*)d_in[3];
    const float* opw = (const float*)d_in[4];
    const float* opb = (const float*)d_in[5];
    const float* pbu = (const float*)d_in[6];
    const float* pbv = (const float*)d_in[7];

    float* out  = (float*)d_out;                          // (B,L,E)
    float* attn = (float*)d_out + (size_t)BB * LL * EE;   // (B,H,L,L)

    const size_t NQ = (size_t)BB * HH * LL * HD;  // 4194304
    float* ctx = (float*)d_ws;                    // 16 MB fp32
    unsigned short* wsu = (unsigned short*)(ctx + (size_t)BB * LL * EE);
    unsigned short* Qu = wsu; wsu += NQ;
    unsigned short* Qv = wsu; wsu += NQ;
    unsigned short* Kw = wsu; wsu += NQ;
    unsigned short* Vt = wsu; wsu += NQ;
    unsigned short* pkb = wsu; wsu += (size_t)HH * PP * HD;

    qkv_kernel<<<dim3(24, 128), 256, 0, stream>>>(x, ipw, pbu, pbv, Qu, Qv, Kw, Vt);
    posk_kernel<<<dim3(8, 32), 256, 0, stream>>>(pe, lpw, pkb);
    attn_kernel<<<dim3(64, 8, 8), 256, 0, stream>>>(Qu, Qv, Kw, Vt, pkb, attn, ctx);
    outproj_kernel<<<dim3(8, 128), 256, 0, stream>>>(ctx, opw, opb, out);
}